// Round 5
// baseline (331.220 us; speedup 1.0000x reference)
//
#include <hip/hip_runtime.h>
#include <cstdint>

#define OWD 126
#define MTOT 15876   // 126*126

typedef short bf16x8 __attribute__((ext_vector_type(8)));
typedef float f32x4  __attribute__((ext_vector_type(4)));

#define BT_ELEMS  (16u * 128u * 1152u)                 // 2,359,296 bf16
#define XBF_ELEMS (16u * 128u * 128u * 128u)           // 33,554,432 bf16
#define WS_NEEDED ((size_t)(BT_ELEMS + XBF_ELEMS) * 2) // ~71.8 MB

__device__ __forceinline__ uint16_t f2bf(float f) {
    union { float f; uint32_t u; } v;
    v.f = f;
    uint32_t u = v.u;
    return (uint16_t)((u + 0x7FFFu + ((u >> 16) & 1u)) >> 16);
}

__device__ __forceinline__ uint32_t pk2(float a, float b) {
    return (uint32_t)f2bf(a) | ((uint32_t)f2bf(b) << 16);
}

__device__ __forceinline__ void gl_lds16(const uint16_t* g, uint16_t* l) {
    __builtin_amdgcn_global_load_lds(
        (const __attribute__((address_space(1))) uint32_t*)g,
        (__attribute__((address_space(3))) uint32_t*)l, 16, 0, 0);
}

// ---------------------------------------------------------------------------
// Prep 1 (round 5): kernel [16][9][128 c][128 n] fp32 -> fragment-major
//   Bt2[b][jt(8)][chunk(36)][l15(16)][quad(4)][8 e] bf16
// where n = jt*16+l15, k = rs*128+c = chunk*32 + quad*8 + e.
// A wave's B fragment for (j,chunk) is then ONE contiguous 1 KB segment:
// lane (l15,quad) loads its own 16 B -> coalesced global->VGPR, no LDS.
// ---------------------------------------------------------------------------
__global__ __launch_bounds__(256) void kprep(const float* __restrict__ Kin,
                                             uint16_t* __restrict__ Bt) {
    const int rs = blockIdx.x;   // 0..8
    const int b  = blockIdx.y;   // 0..15
    const int t  = threadIdx.x;
    const int n  = t & 127;
    const int og = t >> 7;

    const float* src = Kin + (((size_t)b * 9 + rs) << 14);
    const int jt  = n >> 4;
    const int l15 = n & 15;

#pragma unroll
    for (int o = 0; o < 8; ++o) {
        const int oct = og * 8 + o;       // c-octet: c = oct*8 + e
        const float* s0 = src + (oct * 8) * 128 + n;
        uint4 p;
        p.x = pk2(s0[0 * 128], s0[1 * 128]);
        p.y = pk2(s0[2 * 128], s0[3 * 128]);
        p.z = pk2(s0[4 * 128], s0[5 * 128]);
        p.w = pk2(s0[6 * 128], s0[7 * 128]);
        const int chunk = rs * 4 + (oct >> 2);
        const int quad  = oct & 3;
        uint16_t* d = Bt +
            (((((size_t)b * 8 + jt) * 36 + chunk) * 16 + l15) * 4 + quad) * 8;
        *(uint4*)d = p;
    }
}

// Old row-major kprep, used only for the fallback path (ws too small).
__global__ __launch_bounds__(256) void kprep_old(const float* __restrict__ Kin,
                                                 uint16_t* __restrict__ Bt) {
    const int rs = blockIdx.x;
    const int b  = blockIdx.y;
    const int t  = threadIdx.x;
    const int n  = t & 127;
    const int og = t >> 7;

    const float* src = Kin + (((size_t)b * 9 + rs) << 14);
    uint16_t*    dst = Bt + ((size_t)b * 128 + n) * 1152 + rs * 128;

#pragma unroll
    for (int o = 0; o < 8; ++o) {
        const int oct = og * 8 + o;
        const float* s0 = src + (oct * 8) * 128 + n;
        uint4 p;
        p.x = pk2(s0[0 * 128], s0[1 * 128]);
        p.y = pk2(s0[2 * 128], s0[3 * 128]);
        p.z = pk2(s0[4 * 128], s0[5 * 128]);
        p.w = pk2(s0[6 * 128], s0[7 * 128]);
        *(uint4*)(dst + oct * 8) = p;
    }
}

// ---------------------------------------------------------------------------
// Prep 2: X fp32 NHWC -> bf16 NHWC (same layout), 8 elems/thread
// ---------------------------------------------------------------------------
__global__ __launch_bounds__(256) void xprep(const float* __restrict__ X,
                                             uint16_t* __restrict__ Xbf) {
    const size_t i = ((size_t)blockIdx.x * 256 + threadIdx.x) * 8;
    const float4 a = *(const float4*)(X + i);
    const float4 b = *(const float4*)(X + i + 4);
    uint4 p;
    p.x = pk2(a.x, a.y);
    p.y = pk2(a.z, a.w);
    p.z = pk2(b.x, b.y);
    p.w = pk2(b.z, b.w);
    *(uint4*)(Xbf + i) = p;
}

// ---------------------------------------------------------------------------
// Main (round 5): round-4 structure (BK=32, 36 chunks, depth-2 counted-vmcnt
// pipeline, XCD swizzle, verified A-swizzle) with ONE structural change:
// B bypasses LDS. Round-4 LDS pipe was the largest term (~57% busy: 48 KB
// traffic/chunk); B fragments now load straight Bt2(global,L2-resident) ->
// VGPR via the fragment-major layout (coalesced 1KB/wave segments), in 3
// rotating statically-indexed register sets. LDS traffic halves (A only:
// 16 KB read + 8 KB write per chunk); LDS = 3 x 8 KB buffers.
// Operands are bit-identical to round 4 -> correctness preserved.
// vmcnt bookkeeping: per iter issues 4 B-loads + 2 gl_lds; 2-deep prefetch
// -> steady queue 12, wait drains one chunk's worth -> vmcnt(6).
// ---------------------------------------------------------------------------
__global__ __launch_bounds__(256, 3) void conv_mfma_d(const uint16_t* __restrict__ Xbf,
                                                      const uint16_t* __restrict__ Bt,
                                                      float* __restrict__ Out) {
    __shared__ __align__(16) uint16_t lds[3][128 * 32];  // 3 x 8 KB (A only)

    // XCD-aware bijective swizzle (nwg = 125*16 = 2000, 2000 % 8 == 0)
    const int id    = blockIdx.x + 125 * blockIdx.y;
    const int nid   = (id & 7) * 250 + (id >> 3);
    const int mtile = nid % 125;
    const int b     = nid / 125;

    const int tid  = threadIdx.x;
    const int lane = tid & 63;
    const int wave = tid >> 6;
    const int wm   = (wave & 1) << 6;
    const int wn   = (wave >> 1) << 6;
    const int l15  = lane & 15;
    const int quad = lane >> 4;

    // A staging (unchanged, verified): wave w stages rows w*32..w*32+31.
    // load i (0,1): rows w*32+i*16+(lane>>2), phys slot lane&3,
    // logical chunk kc = (lane&3) ^ ((row>>1)&3) = (lane&3) ^ ((lane>>3)&3)
    const int l2 = lane >> 2;
    const int kc = (lane & 3) ^ ((lane >> 3) & 3);
    const uint16_t* Asrc[2];
#pragma unroll
    for (int i = 0; i < 2; ++i) {
        const int row = wave * 32 + i * 16 + l2;
        int m = mtile * 128 + row;
        if (m >= MTOT) m = MTOT - 1;
        const int oh = m / OWD, ow = m - oh * OWD;
        Asrc[i] = Xbf + (((size_t)b * 128 + oh) * 128 + ow) * 128 + kc * 8;
    }
    const int dbase = wave * 1024 + lane * 8;  // elem offset in an A buffer

    // B fragment base pointers: rB[j] for chunk t lives at Bp[j] + t*512 elems
    const uint16_t* Bp[4];
#pragma unroll
    for (int j = 0; j < 4; ++j)
        Bp[j] = Bt + ((((size_t)b * 8 + (wn >> 4) + j) * 36 * 16 * 4)
                      + ((size_t)l15 * 4 + quad)) * 8;

    f32x4 acc[4][4];
#pragma unroll
    for (int i = 0; i < 4; ++i)
#pragma unroll
        for (int j = 0; j < 4; ++j)
            acc[i][j] = (f32x4){0.f, 0.f, 0.f, 0.f};

    bf16x8 rB0[4], rB1[4], rB2[4];  // 3 rotating B sets, static indexing

    // chunk t (0..35): rs = t>>2, ch base c0 = (t&3)*32
#define STAGE(t_, bu_)                                                      \
    {                                                                       \
        const int rs_ = (t_) >> 2;                                         \
        const int c0_ = ((t_) & 3) << 5;                                   \
        const int r_  = (rs_ * 11) >> 5; /* rs/3 for rs<9 */               \
        const int s_  = rs_ - r_ * 3;                                      \
        const int ao_ = (r_ * 128 + s_) * 128 + c0_;                       \
        uint16_t* Ad_ = &lds[bu_][dbase];                                  \
        _Pragma("unroll")                                                  \
        for (int i_ = 0; i_ < 2; ++i_)                                     \
            gl_lds16(Asrc[i_] + ao_, Ad_ + i_ * 512);                      \
    }

#define LOADB(t_, r_)                                                       \
    {                                                                       \
        _Pragma("unroll")                                                  \
        for (int j_ = 0; j_ < 4; ++j_)                                     \
            r_[j_] = *(const bf16x8*)(Bp[j_] + (size_t)(t_) * 512);        \
    }

#define COMPUTE(bu_, r_)                                                    \
    {                                                                       \
        bf16x8 af[4];                                                      \
        _Pragma("unroll")                                                  \
        for (int i_ = 0; i_ < 4; ++i_) {                                   \
            const int row_ = wm + i_ * 16 + l15;                           \
            const int sl_  = quad ^ ((row_ >> 1) & 3);                     \
            af[i_] = *(const bf16x8*)&lds[bu_][row_ * 32 + sl_ * 8];       \
        }                                                                  \
        _Pragma("unroll")                                                  \
        for (int i_ = 0; i_ < 4; ++i_)                                     \
            _Pragma("unroll")                                              \
            for (int j_ = 0; j_ < 4; ++j_)                                 \
                acc[i_][j_] = __builtin_amdgcn_mfma_f32_16x16x32_bf16(     \
                    af[i_], r_[j_], acc[i_][j_], 0, 0, 0);                 \
    }

#define WAITBAR(n_)                                                         \
    asm volatile("s_waitcnt vmcnt(" #n_ ")" ::: "memory");                 \
    __builtin_amdgcn_s_barrier();                                          \
    __builtin_amdgcn_sched_barrier(0);

    // ITER(t): wait chunk t's B+A (leaves t+1's 6 ops in flight), then issue
    // chunk t+2's loads, then compute t.
#define ITER(t_, rc_, rl_, bc_, bl_)                                        \
    {                                                                       \
        WAITBAR(6);                                                        \
        LOADB((t_) + 2, rl_);                                              \
        STAGE((t_) + 2, bl_);                                              \
        COMPUTE(bc_, rc_);                                                 \
    }

    // prologue: chunks 0,1 (queue: B0:4, A0:2, B1:4, A1:2 = 12)
    LOADB(0, rB0);
    STAGE(0, 0);
    LOADB(1, rB1);
    STAGE(1, 1);

#pragma unroll 1
    for (int t = 0; t < 33; t += 3) {
        ITER(t,     rB0, rB2, 0, 2);
        ITER(t + 1, rB1, rB0, 1, 0);
        ITER(t + 2, rB2, rB1, 2, 1);
    }
    ITER(33, rB0, rB2, 0, 2);   // loads chunk 35 into set2/buf2
    // t=34: queue = B34:4 A34:2 B35:4 A35:2 -> drain 34's
    WAITBAR(6);
    COMPUTE(1, rB1);
    // t=35: drain the rest
    WAITBAR(0);
    COMPUTE(2, rB2);

#undef STAGE
#undef LOADB
#undef COMPUTE
#undef WAITBAR
#undef ITER

    // epilogue: D row = quad*4+reg, col = lane&15 (verified)
#pragma unroll
    for (int i = 0; i < 4; ++i) {
#pragma unroll
        for (int rr = 0; rr < 4; ++rr) {
            const int mrow = mtile * 128 + wm + i * 16 + quad * 4 + rr;
            if (mrow < MTOT) {
                const int oh2 = mrow / OWD;
                const int ow2 = mrow - oh2 * OWD;
                float* op = Out + (((size_t)b * OWD + oh2) * OWD + ow2) * 128 + wn + l15;
#pragma unroll
                for (int j = 0; j < 4; ++j)
                    op[j * 16] = acc[i][j][rr];
            }
        }
    }
}

// ---------------------------------------------------------------------------
// Fallback (ws too small): fp32 X with in-kernel cvt, row-major Bt
// (paired with kprep_old; unchanged, verified).
// ---------------------------------------------------------------------------
__global__ __launch_bounds__(256) void conv_mfma(const float* __restrict__ X,
                                                 const uint16_t* __restrict__ Bt,
                                                 float* __restrict__ Out) {
    __shared__ __align__(16) uint16_t lA[128 * 64];
    __shared__ __align__(16) uint16_t lB[128 * 64];

    const int mtile = blockIdx.x;
    const int b     = blockIdx.y;
    const int tid   = threadIdx.x;
    const int lane  = tid & 63;
    const int wave  = tid >> 6;
    const int wm    = (wave & 1) << 6;
    const int wn    = (wave >> 1) << 6;
    const int l15   = lane & 15;
    const int quad  = lane >> 4;

    const int srow  = tid >> 1;
    const int shalf = tid & 1;

    int m = mtile * 128 + srow;
    if (m >= MTOT) m = MTOT - 1;
    const int oh = m / OWD;
    const int ow = m - oh * OWD;
    const float*    Xb = X + (((size_t)b * 128 + oh) * 128 + ow) * 128;
    const uint16_t* Bb = Bt + ((size_t)b * 128 + srow) * 1152 + shalf * 32;

    f32x4 acc[4][4];
#pragma unroll
    for (int i = 0; i < 4; ++i)
#pragma unroll
        for (int j = 0; j < 4; ++j)
            acc[i][j] = (f32x4){0.f, 0.f, 0.f, 0.f};

    for (int chunk = 0; chunk < 18; ++chunk) {
        const int rs = chunk >> 1;
        const int c0 = (chunk & 1) << 6;
        const int r  = rs / 3;
        const int s  = rs - r * 3;

        __syncthreads();
        {
            const float4* src = (const float4*)(Xb + (r * 128 + s) * 128 + c0 + shalf * 32);
            float4 v[8];
#pragma unroll
            for (int i = 0; i < 8; ++i) v[i] = src[i];
#pragma unroll
            for (int i = 0; i < 4; ++i) {
                uint4 p;
                p.x = pk2(v[2 * i].x, v[2 * i].y);
                p.y = pk2(v[2 * i].z, v[2 * i].w);
                p.z = pk2(v[2 * i + 1].x, v[2 * i + 1].y);
                p.w = pk2(v[2 * i + 1].z, v[2 * i + 1].w);
                const int ci = (shalf * 4 + i) ^ (srow & 7);
                *(uint4*)&lA[srow * 64 + ci * 8] = p;
            }
        }
        {
            const uint4* bsrc = (const uint4*)(Bb + rs * 128 + c0);
#pragma unroll
            for (int i = 0; i < 4; ++i) {
                const uint4 p = bsrc[i];
                const int ci = (shalf * 4 + i) ^ (srow & 7);
                *(uint4*)&lB[srow * 64 + ci * 8] = p;
            }
        }
        __syncthreads();

#pragma unroll
        for (int ksub = 0; ksub < 2; ++ksub) {
            bf16x8 af[4], bfr[4];
#pragma unroll
            for (int i = 0; i < 4; ++i) {
                const int row = wm + i * 16 + l15;
                const int ci  = (ksub * 4 + quad) ^ (row & 7);
                af[i] = *(const bf16x8*)&lA[row * 64 + ci * 8];
            }
#pragma unroll
            for (int j = 0; j < 4; ++j) {
                const int row = wn + j * 16 + l15;
                const int ci  = (ksub * 4 + quad) ^ (row & 7);
                bfr[j] = *(const bf16x8*)&lB[row * 64 + ci * 8];
            }
#pragma unroll
            for (int i = 0; i < 4; ++i)
#pragma unroll
                for (int j = 0; j < 4; ++j)
                    acc[i][j] = __builtin_amdgcn_mfma_f32_16x16x32_bf16(
                        af[i], bfr[j], acc[i][j], 0, 0, 0);
        }
    }

#pragma unroll
    for (int i = 0; i < 4; ++i) {
#pragma unroll
        for (int rr = 0; rr < 4; ++rr) {
            const int mrow = mtile * 128 + wm + i * 16 + quad * 4 + rr;
            if (mrow < MTOT) {
                const int oh2 = mrow / OWD;
                const int ow2 = mrow - oh2 * OWD;
                float* op = Out + (((size_t)b * OWD + oh2) * OWD + ow2) * 128 + wn + l15;
#pragma unroll
                for (int j = 0; j < 4; ++j)
                    op[j * 16] = acc[i][j][rr];
            }
        }
    }
}

extern "C" void kernel_launch(void* const* d_in, const int* in_sizes, int n_in,
                              void* d_out, int out_size, void* d_ws, size_t ws_size,
                              hipStream_t stream) {
    const float* X   = (const float*)d_in[0];   // [16,128,128,128]
    const float* Kin = (const float*)d_in[1];   // [16,3,3,128,128]
    float*       Out = (float*)d_out;           // [16,126,126,128]
    uint16_t*    Bt  = (uint16_t*)d_ws;         // bf16 (layout depends on path)
    uint16_t*    Xbf = Bt + BT_ELEMS;           // bf16 [16][128][128][128]

    if (ws_size >= WS_NEEDED) {
        kprep<<<dim3(9, 16), 256, 0, stream>>>(Kin, Bt);        // fragment-major
        xprep<<<XBF_ELEMS / (256 * 8), 256, 0, stream>>>(X, Xbf);
        conv_mfma_d<<<dim3(125, 16), 256, 0, stream>>>(Xbf, Bt, Out);
    } else {
        kprep_old<<<dim3(9, 16), 256, 0, stream>>>(Kin, Bt);    // row-major
        conv_mfma<<<dim3(125, 16), 256, 0, stream>>>(X, Bt, Out);
    }
}

// Round 6
// 318.953 us; speedup vs baseline: 1.0385x; 1.0385x over previous
//
#include <hip/hip_runtime.h>
#include <cstdint>

#define OWD 126
#define MTOT 15876   // 126*126

typedef short bf16x8 __attribute__((ext_vector_type(8)));
typedef float f32x4  __attribute__((ext_vector_type(4)));

#define BT_ELEMS  (16u * 128u * 1152u)                 // 2,359,296 bf16
#define XBF_ELEMS (16u * 128u * 128u * 128u)           // 33,554,432 bf16
#define WS_NEEDED ((size_t)(BT_ELEMS + XBF_ELEMS) * 2) // ~71.8 MB

__device__ __forceinline__ uint16_t f2bf(float f) {
    union { float f; uint32_t u; } v;
    v.f = f;
    uint32_t u = v.u;
    return (uint16_t)((u + 0x7FFFu + ((u >> 16) & 1u)) >> 16);
}

__device__ __forceinline__ uint32_t pk2(float a, float b) {
    return (uint32_t)f2bf(a) | ((uint32_t)f2bf(b) << 16);
}

__device__ __forceinline__ void gl_lds16(const uint16_t* g, uint16_t* l) {
    __builtin_amdgcn_global_load_lds(
        (const __attribute__((address_space(1))) uint32_t*)g,
        (__attribute__((address_space(3))) uint32_t*)l, 16, 0, 0);
}

// ---------------------------------------------------------------------------
// Prep 1: kernel [16][9][128 c][128 n] fp32 -> Bt [16][128 n][1152 k] bf16
// ---------------------------------------------------------------------------
__global__ __launch_bounds__(256) void kprep(const float* __restrict__ Kin,
                                             uint16_t* __restrict__ Bt) {
    const int rs = blockIdx.x;   // 0..8
    const int b  = blockIdx.y;   // 0..15
    const int t  = threadIdx.x;
    const int n  = t & 127;
    const int og = t >> 7;

    const float* src = Kin + (((size_t)b * 9 + rs) << 14);
    uint16_t*    dst = Bt + ((size_t)b * 128 + n) * 1152 + rs * 128;

#pragma unroll
    for (int o = 0; o < 8; ++o) {
        const int oct = og * 8 + o;
        const float* s0 = src + (oct * 8) * 128 + n;
        uint4 p;
        p.x = pk2(s0[0 * 128], s0[1 * 128]);
        p.y = pk2(s0[2 * 128], s0[3 * 128]);
        p.z = pk2(s0[4 * 128], s0[5 * 128]);
        p.w = pk2(s0[6 * 128], s0[7 * 128]);
        *(uint4*)(dst + oct * 8) = p;
    }
}

// ---------------------------------------------------------------------------
// Prep 2: X fp32 NHWC -> bf16 NHWC (same layout), 8 elems/thread
// ---------------------------------------------------------------------------
__global__ __launch_bounds__(256) void xprep(const float* __restrict__ X,
                                             uint16_t* __restrict__ Xbf) {
    const size_t i = ((size_t)blockIdx.x * 256 + threadIdx.x) * 8;
    const float4 a = *(const float4*)(X + i);
    const float4 b = *(const float4*)(X + i + 4);
    uint4 p;
    p.x = pk2(a.x, a.y);
    p.y = pk2(a.z, a.w);
    p.z = pk2(b.x, b.y);
    p.w = pk2(b.z, b.w);
    *(uint4*)(Xbf + i) = p;
}

// ---------------------------------------------------------------------------
// Main (round 6): EXACT round-4 kernel (best measured: 104us; BK=32, 36
// chunks, 3x16KB LDS bufs, depth-2 counted vmcnt(4) pipeline, XCD swizzle,
// conflict-free slot = q ^ ((row>>1)&3) involution) + ONE change: T5
// s_setprio(1)/(0) around the 16-MFMA cluster. Corpus: +21-39% on
// counted-vmcnt phase-split schedules (m218b/m224); null on lockstep
// single-phase (m190). Our loop qualifies: waves alternate load-issue /
// MFMA roles and ~3 independent blocks share each SIMD at uncorrelated
// phases. Pre-committed read: null => need 2-waves-per-SIMD restructure.
// Rounds 2/5 (B bypassing LDS) both regressed -- B stays in LDS.
// ---------------------------------------------------------------------------
__global__ __launch_bounds__(256) void conv_mfma_c(const uint16_t* __restrict__ Xbf,
                                                   const uint16_t* __restrict__ Bt,
                                                   float* __restrict__ Out) {
    __shared__ __align__(16) uint16_t lds[3][256 * 32];  // 3 x 16 KB

    // XCD-aware bijective swizzle (nwg = 125*16 = 2000, 2000 % 8 == 0)
    const int id    = blockIdx.x + 125 * blockIdx.y;
    const int nid   = (id & 7) * 250 + (id >> 3);
    const int mtile = nid % 125;
    const int b     = nid / 125;

    const int tid  = threadIdx.x;
    const int lane = tid & 63;
    const int wave = tid >> 6;
    const int wm   = (wave & 1) << 6;
    const int wn   = (wave >> 1) << 6;
    const int l15  = lane & 15;
    const int quad = lane >> 4;

    // staging: wave w stages A rows w*32..w*32+31 and B rows w*32..w*32+31.
    // load i (0,1): rows w*32+i*16+(lane>>2), phys slot lane&3,
    // logical chunk kc = (lane&3) ^ ((row>>1)&3) = (lane&3) ^ ((lane>>3)&3)
    const int l2 = lane >> 2;
    const int kc = (lane & 3) ^ ((lane >> 3) & 3);
    const uint16_t* Asrc[2];
    const uint16_t* Bsrc[2];
#pragma unroll
    for (int i = 0; i < 2; ++i) {
        const int row = wave * 32 + i * 16 + l2;
        int m = mtile * 128 + row;
        if (m >= MTOT) m = MTOT - 1;
        const int oh = m / OWD, ow = m - oh * OWD;
        Asrc[i] = Xbf + (((size_t)b * 128 + oh) * 128 + ow) * 128 + kc * 8;
        Bsrc[i] = Bt + ((size_t)b * 128 + row) * 1152 + kc * 8;
    }
    const int dbase = wave * 1024 + lane * 8;  // elem offset in a buffer

    f32x4 acc[4][4];
#pragma unroll
    for (int i = 0; i < 4; ++i)
#pragma unroll
        for (int j = 0; j < 4; ++j)
            acc[i][j] = (f32x4){0.f, 0.f, 0.f, 0.f};

    // chunk t (0..35): rs = t>>2, ch base c0 = (t&3)*32
#define STAGE(t_, bu_)                                                      \
    {                                                                       \
        const int rs_ = (t_) >> 2;                                         \
        const int c0_ = ((t_) & 3) << 5;                                   \
        const int r_  = (rs_ * 11) >> 5; /* rs/3 for rs<9 */               \
        const int s_  = rs_ - r_ * 3;                                      \
        const int ao_ = (r_ * 128 + s_) * 128 + c0_;                       \
        const int bo_ = rs_ * 128 + c0_;                                   \
        uint16_t* Ad_ = &lds[bu_][dbase];                                  \
        uint16_t* Bd_ = &lds[bu_][4096 + dbase];                           \
        _Pragma("unroll")                                                  \
        for (int i_ = 0; i_ < 2; ++i_) {                                   \
            gl_lds16(Asrc[i_] + ao_, Ad_ + i_ * 512);                      \
            gl_lds16(Bsrc[i_] + bo_, Bd_ + i_ * 512);                      \
        }                                                                  \
    }

#define COMPUTE(bu_)                                                        \
    {                                                                       \
        bf16x8 af[4], bfr[4];                                              \
        _Pragma("unroll")                                                  \
        for (int i_ = 0; i_ < 4; ++i_) {                                   \
            const int row_ = wm + i_ * 16 + l15;                           \
            const int sl_  = quad ^ ((row_ >> 1) & 3);                     \
            af[i_] = *(const bf16x8*)&lds[bu_][row_ * 32 + sl_ * 8];       \
        }                                                                  \
        _Pragma("unroll")                                                  \
        for (int j_ = 0; j_ < 4; ++j_) {                                   \
            const int row_ = wn + j_ * 16 + l15;                           \
            const int sl_  = quad ^ ((row_ >> 1) & 3);                     \
            bfr[j_] = *(const bf16x8*)&lds[bu_][4096 + row_ * 32 + sl_ * 8];\
        }                                                                  \
        __builtin_amdgcn_s_setprio(1);                                     \
        _Pragma("unroll")                                                  \
        for (int i_ = 0; i_ < 4; ++i_)                                     \
            _Pragma("unroll")                                              \
            for (int j_ = 0; j_ < 4; ++j_)                                 \
                acc[i_][j_] = __builtin_amdgcn_mfma_f32_16x16x32_bf16(     \
                    af[i_], bfr[j_], acc[i_][j_], 0, 0, 0);                \
        __builtin_amdgcn_s_setprio(0);                                     \
    }

#define WAITBAR4                                                            \
    asm volatile("s_waitcnt vmcnt(4)" ::: "memory");                       \
    __builtin_amdgcn_s_barrier();                                          \
    __builtin_amdgcn_sched_barrier(0);

#define ITER(t_, bc_, bs_)                                                  \
    {                                                                       \
        WAITBAR4;                                                          \
        STAGE((t_) + 2, bs_);                                              \
        COMPUTE(bc_);                                                      \
    }

    // prologue: chunks 0,1 into bufs 0,1 (8 loads in flight)
    STAGE(0, 0);
    STAGE(1, 1);

    // steady state: compute t from buf t%3, stage t+2 into (t+2)%3.
    // At each wait: outstanding = chunk t (4) + chunk t+1 (4); vmcnt(4)
    // drains t's, leaves t+1's in flight across the barrier.
#pragma unroll 1
    for (int t = 0; t < 33; t += 3) {
        ITER(t, 0, 2);
        ITER(t + 1, 1, 0);
        ITER(t + 2, 2, 1);
    }
    ITER(33, 0, 2);  // stages chunk 35 into buf 2
    // t = 34: outstanding = 34's + 35's -> drain 34's
    WAITBAR4;
    COMPUTE(1);
    // t = 35: drain the last 4
    asm volatile("s_waitcnt vmcnt(0)" ::: "memory");
    __builtin_amdgcn_s_barrier();
    __builtin_amdgcn_sched_barrier(0);
    COMPUTE(2);

#undef STAGE
#undef COMPUTE
#undef WAITBAR4
#undef ITER

    // epilogue: D row = quad*4+reg, col = lane&15 (verified)
#pragma unroll
    for (int i = 0; i < 4; ++i) {
#pragma unroll
        for (int rr = 0; rr < 4; ++rr) {
            const int mrow = mtile * 128 + wm + i * 16 + quad * 4 + rr;
            if (mrow < MTOT) {
                const int oh2 = mrow / OWD;
                const int ow2 = mrow - oh2 * OWD;
                float* op = Out + (((size_t)b * OWD + oh2) * OWD + ow2) * 128 + wn + l15;
#pragma unroll
                for (int j = 0; j < 4; ++j)
                    op[j * 16] = acc[i][j][rr];
            }
        }
    }
}

// ---------------------------------------------------------------------------
// Fallback (ws too small): fp32 X with in-kernel cvt (unchanged, verified).
// ---------------------------------------------------------------------------
__global__ __launch_bounds__(256) void conv_mfma(const float* __restrict__ X,
                                                 const uint16_t* __restrict__ Bt,
                                                 float* __restrict__ Out) {
    __shared__ __align__(16) uint16_t lA[128 * 64];
    __shared__ __align__(16) uint16_t lB[128 * 64];

    const int mtile = blockIdx.x;
    const int b     = blockIdx.y;
    const int tid   = threadIdx.x;
    const int lane  = tid & 63;
    const int wave  = tid >> 6;
    const int wm    = (wave & 1) << 6;
    const int wn    = (wave >> 1) << 6;
    const int l15   = lane & 15;
    const int quad  = lane >> 4;

    const int srow  = tid >> 1;
    const int shalf = tid & 1;

    int m = mtile * 128 + srow;
    if (m >= MTOT) m = MTOT - 1;
    const int oh = m / OWD;
    const int ow = m - oh * OWD;
    const float*    Xb = X + (((size_t)b * 128 + oh) * 128 + ow) * 128;
    const uint16_t* Bb = Bt + ((size_t)b * 128 + srow) * 1152 + shalf * 32;

    f32x4 acc[4][4];
#pragma unroll
    for (int i = 0; i < 4; ++i)
#pragma unroll
        for (int j = 0; j < 4; ++j)
            acc[i][j] = (f32x4){0.f, 0.f, 0.f, 0.f};

    for (int chunk = 0; chunk < 18; ++chunk) {
        const int rs = chunk >> 1;
        const int c0 = (chunk & 1) << 6;
        const int r  = rs / 3;
        const int s  = rs - r * 3;

        __syncthreads();
        {
            const float4* src = (const float4*)(Xb + (r * 128 + s) * 128 + c0 + shalf * 32);
            float4 v[8];
#pragma unroll
            for (int i = 0; i < 8; ++i) v[i] = src[i];
#pragma unroll
            for (int i = 0; i < 4; ++i) {
                uint4 p;
                p.x = pk2(v[2 * i].x, v[2 * i].y);
                p.y = pk2(v[2 * i].z, v[2 * i].w);
                p.z = pk2(v[2 * i + 1].x, v[2 * i + 1].y);
                p.w = pk2(v[2 * i + 1].z, v[2 * i + 1].w);
                const int ci = (shalf * 4 + i) ^ (srow & 7);
                *(uint4*)&lA[srow * 64 + ci * 8] = p;
            }
        }
        {
            const uint4* bsrc = (const uint4*)(Bb + rs * 128 + c0);
#pragma unroll
            for (int i = 0; i < 4; ++i) {
                const uint4 p = bsrc[i];
                const int ci = (shalf * 4 + i) ^ (srow & 7);
                *(uint4*)&lB[srow * 64 + ci * 8] = p;
            }
        }
        __syncthreads();

#pragma unroll
        for (int ksub = 0; ksub < 2; ++ksub) {
            bf16x8 af[4], bfr[4];
#pragma unroll
            for (int i = 0; i < 4; ++i) {
                const int row = wm + i * 16 + l15;
                const int ci  = (ksub * 4 + quad) ^ (row & 7);
                af[i] = *(const bf16x8*)&lA[row * 64 + ci * 8];
            }
#pragma unroll
            for (int j = 0; j < 4; ++j) {
                const int row = wn + j * 16 + l15;
                const int ci  = (ksub * 4 + quad) ^ (row & 7);
                bfr[j] = *(const bf16x8*)&lB[row * 64 + ci * 8];
            }
#pragma unroll
            for (int i = 0; i < 4; ++i)
#pragma unroll
                for (int j = 0; j < 4; ++j)
                    acc[i][j] = __builtin_amdgcn_mfma_f32_16x16x32_bf16(
                        af[i], bfr[j], acc[i][j], 0, 0, 0);
        }
    }

#pragma unroll
    for (int i = 0; i < 4; ++i) {
#pragma unroll
        for (int rr = 0; rr < 4; ++rr) {
            const int mrow = mtile * 128 + wm + i * 16 + quad * 4 + rr;
            if (mrow < MTOT) {
                const int oh2 = mrow / OWD;
                const int ow2 = mrow - oh2 * OWD;
                float* op = Out + (((size_t)b * OWD + oh2) * OWD + ow2) * 128 + wn + l15;
#pragma unroll
                for (int j = 0; j < 4; ++j)
                    op[j * 16] = acc[i][j][rr];
            }
        }
    }
}

extern "C" void kernel_launch(void* const* d_in, const int* in_sizes, int n_in,
                              void* d_out, int out_size, void* d_ws, size_t ws_size,
                              hipStream_t stream) {
    const float* X   = (const float*)d_in[0];   // [16,128,128,128]
    const float* Kin = (const float*)d_in[1];   // [16,3,3,128,128]
    float*       Out = (float*)d_out;           // [16,126,126,128]
    uint16_t*    Bt  = (uint16_t*)d_ws;         // bf16 [16][128][1152]
    uint16_t*    Xbf = Bt + BT_ELEMS;           // bf16 [16][128][128][128]

    kprep<<<dim3(9, 16), 256, 0, stream>>>(Kin, Bt);
    if (ws_size >= WS_NEEDED) {
        xprep<<<XBF_ELEMS / (256 * 8), 256, 0, stream>>>(X, Xbf);
        conv_mfma_c<<<dim3(125, 16), 256, 0, stream>>>(Xbf, Bt, Out);
    } else {
        conv_mfma<<<dim3(125, 16), 256, 0, stream>>>(X, Bt, Out);
    }
}

// Round 7
// 316.515 us; speedup vs baseline: 1.0465x; 1.0077x over previous
//
#include <hip/hip_runtime.h>
#include <cstdint>

#define OWD 126
#define MTOT 15876   // 126*126

typedef short bf16x8 __attribute__((ext_vector_type(8)));
typedef float f32x4  __attribute__((ext_vector_type(4)));

#define BT_ELEMS  (16u * 128u * 1152u)                 // 2,359,296 bf16
#define XBF_ELEMS (16u * 128u * 128u * 128u)           // 33,554,432 bf16
#define WS_NEEDED ((size_t)(BT_ELEMS + XBF_ELEMS) * 2) // ~71.8 MB

__device__ __forceinline__ uint16_t f2bf(float f) {
    union { float f; uint32_t u; } v;
    v.f = f;
    uint32_t u = v.u;
    return (uint16_t)((u + 0x7FFFu + ((u >> 16) & 1u)) >> 16);
}

__device__ __forceinline__ uint32_t pk2(float a, float b) {
    return (uint32_t)f2bf(a) | ((uint32_t)f2bf(b) << 16);
}

__device__ __forceinline__ void gl_lds16(const uint16_t* g, uint16_t* l) {
    __builtin_amdgcn_global_load_lds(
        (const __attribute__((address_space(1))) uint32_t*)g,
        (__attribute__((address_space(3))) uint32_t*)l, 16, 0, 0);
}

// ---------------------------------------------------------------------------
// Prep 1: kernel [16][9][128 c][128 n] fp32 -> Bt [16][128 n][1152 k] bf16
// ---------------------------------------------------------------------------
__global__ __launch_bounds__(256) void kprep(const float* __restrict__ Kin,
                                             uint16_t* __restrict__ Bt) {
    const int rs = blockIdx.x;   // 0..8
    const int b  = blockIdx.y;   // 0..15
    const int t  = threadIdx.x;
    const int n  = t & 127;
    const int og = t >> 7;

    const float* src = Kin + (((size_t)b * 9 + rs) << 14);
    uint16_t*    dst = Bt + ((size_t)b * 128 + n) * 1152 + rs * 128;

#pragma unroll
    for (int o = 0; o < 8; ++o) {
        const int oct = og * 8 + o;
        const float* s0 = src + (oct * 8) * 128 + n;
        uint4 p;
        p.x = pk2(s0[0 * 128], s0[1 * 128]);
        p.y = pk2(s0[2 * 128], s0[3 * 128]);
        p.z = pk2(s0[4 * 128], s0[5 * 128]);
        p.w = pk2(s0[6 * 128], s0[7 * 128]);
        *(uint4*)(dst + oct * 8) = p;
    }
}

// ---------------------------------------------------------------------------
// Prep 2: X fp32 NHWC -> bf16 NHWC (same layout), 8 elems/thread
// ---------------------------------------------------------------------------
__global__ __launch_bounds__(256) void xprep(const float* __restrict__ X,
                                             uint16_t* __restrict__ Xbf) {
    const size_t i = ((size_t)blockIdx.x * 256 + threadIdx.x) * 8;
    const float4 a = *(const float4*)(X + i);
    const float4 b = *(const float4*)(X + i + 4);
    uint4 p;
    p.x = pk2(a.x, a.y);
    p.y = pk2(a.z, a.w);
    p.z = pk2(b.x, b.y);
    p.w = pk2(b.z, b.w);
    *(uint4*)(Xbf + i) = p;
}

// ---------------------------------------------------------------------------
// Main (round 7): 8-wave restructure (the pre-committed branch after T5's
// null on the 4-wave loop). Block tile 256x128, 512 threads = 8 waves
// (4M x 2N, wave tile 64x64 unchanged, acc 4x4). BK=64 -> 18 K-steps,
// 32 MFMA per wave per barrier (2x round 4), barriers halved. 2 waves/SIMD
// inside one block: while one wave runs its MFMA cluster its SIMD-partner
// issues ds_reads/gl_lds -> the role diversity that T5/overlap needs
// (m218b regime). Sync = round-4's proven counted pattern, scaled:
// 6 gl_lds/thread/K-step, 3 x 48KB LDS buffers (144 KB), depth-2 prefetch,
// { s_waitcnt vmcnt(6); s_barrier; sched_barrier } once per K-step --
// one full K-step always in flight across the barrier.
// Layout involutions are the round-0/1 verified pair (0 conflicts, correct):
//   rows 128 B (64 bf16) of 8 x 16B slots; logical slot kc of row r lives
//   at kc^(r&7); staging lane l fetches kc=(l&7)^(l>>3); reads use slot
//   (h*4+quad)^(row&7).
// Grid 63x16 = 1008 blocks (1008%8==0), XCD swizzle kept (FETCH 122->38MB).
// ---------------------------------------------------------------------------
__global__ __launch_bounds__(512, 2) void conv_mfma_e(const uint16_t* __restrict__ Xbf,
                                                      const uint16_t* __restrict__ Bt,
                                                      float* __restrict__ Out) {
    // per buffer: A [256 rows][64] at [0,16384), B [128 rows][64] at [16384,24576)
    __shared__ __align__(16) uint16_t lds[3][24576];  // 3 x 48 KB = 144 KB

    // XCD-aware bijective swizzle (nwg = 63*16 = 1008, 1008 % 8 == 0)
    const int id    = blockIdx.x + 63 * blockIdx.y;
    const int nid   = (id & 7) * 126 + (id >> 3);
    const int mtile = nid % 63;
    const int b     = nid / 63;

    const int tid  = threadIdx.x;
    const int lane = tid & 63;
    const int wave = tid >> 6;
    const int wm   = (wave & 3) << 6;   // 0/64/128/192
    const int wn   = (wave >> 2) << 6;  // 0/64
    const int l15  = lane & 15;
    const int quad = lane >> 4;

    // staging (verified involution): pass p covers A rows p*64 + wave*8 + (lane>>3)
    // (B: pass q, rows q*64 + wave*8 + (lane>>3)); phys slot lane&7,
    // logical chunk kc = (lane&7) ^ (row&7) = (lane&7) ^ (lane>>3)
    const int kc = (lane & 7) ^ (lane >> 3);
    const uint16_t* Asrc[4];
    const uint16_t* Bsrc[2];
#pragma unroll
    for (int p = 0; p < 4; ++p) {
        const int row = p * 64 + wave * 8 + (lane >> 3);
        int m = mtile * 256 + row;
        if (m >= MTOT) m = MTOT - 1;
        const int oh = m / OWD, ow = m - oh * OWD;
        Asrc[p] = Xbf + (((size_t)b * 128 + oh) * 128 + ow) * 128 + kc * 8;
    }
#pragma unroll
    for (int q = 0; q < 2; ++q) {
        const int row = q * 64 + wave * 8 + (lane >> 3);
        Bsrc[q] = Bt + ((size_t)b * 128 + row) * 1152 + kc * 8;
    }
    const int dbase = tid * 8;  // elem offset: wave-uniform base + lane*16B

    f32x4 acc[4][4];
#pragma unroll
    for (int i = 0; i < 4; ++i)
#pragma unroll
        for (int j = 0; j < 4; ++j)
            acc[i][j] = (f32x4){0.f, 0.f, 0.f, 0.f};

    // K-step t (0..17): rs = t>>1, k-half c0 = (t&1)*64
#define STAGE(t_, bu_)                                                      \
    {                                                                       \
        const int rs_ = (t_) >> 1;                                         \
        const int c0_ = ((t_) & 1) << 6;                                   \
        const int r_  = (rs_ * 11) >> 5; /* rs/3 for rs<9 */               \
        const int s_  = rs_ - r_ * 3;                                      \
        const int ao_ = (r_ * 128 + s_) * 128 + c0_;                       \
        const int bo_ = rs_ * 128 + c0_;                                   \
        uint16_t* base_ = &lds[bu_][0];                                    \
        _Pragma("unroll")                                                  \
        for (int p_ = 0; p_ < 4; ++p_)                                     \
            gl_lds16(Asrc[p_] + ao_, base_ + p_ * 4096 + dbase);           \
        _Pragma("unroll")                                                  \
        for (int q_ = 0; q_ < 2; ++q_)                                     \
            gl_lds16(Bsrc[q_] + bo_, base_ + 16384 + q_ * 4096 + dbase);   \
    }

#define COMPUTE(bu_)                                                        \
    {                                                                       \
        bf16x8 af[2][4], bfr[2][4];                                        \
        _Pragma("unroll")                                                  \
        for (int h_ = 0; h_ < 2; ++h_) {                                   \
            _Pragma("unroll")                                              \
            for (int i_ = 0; i_ < 4; ++i_) {                               \
                const int row_ = wm + i_ * 16 + l15;                       \
                const int sl_  = (h_ * 4 + quad) ^ (row_ & 7);             \
                af[h_][i_] = *(const bf16x8*)&lds[bu_][row_ * 64 + sl_ * 8];\
            }                                                              \
            _Pragma("unroll")                                              \
            for (int j_ = 0; j_ < 4; ++j_) {                               \
                const int row_ = wn + j_ * 16 + l15;                       \
                const int sl_  = (h_ * 4 + quad) ^ (row_ & 7);             \
                bfr[h_][j_] = *(const bf16x8*)&lds[bu_][16384 + row_ * 64 + sl_ * 8];\
            }                                                              \
        }                                                                  \
        __builtin_amdgcn_s_setprio(1);                                     \
        _Pragma("unroll")                                                  \
        for (int h_ = 0; h_ < 2; ++h_)                                     \
            _Pragma("unroll")                                              \
            for (int i_ = 0; i_ < 4; ++i_)                                 \
                _Pragma("unroll")                                          \
                for (int j_ = 0; j_ < 4; ++j_)                             \
                    acc[i_][j_] = __builtin_amdgcn_mfma_f32_16x16x32_bf16( \
                        af[h_][i_], bfr[h_][j_], acc[i_][j_], 0, 0, 0);    \
        __builtin_amdgcn_s_setprio(0);                                     \
    }

#define WAITBAR(n_)                                                         \
    asm volatile("s_waitcnt vmcnt(" #n_ ")" ::: "memory");                 \
    __builtin_amdgcn_s_barrier();                                          \
    __builtin_amdgcn_sched_barrier(0);

    // ITER(t): drain K-step t's 6 loads (leaves t+1's 6 in flight across the
    // barrier), issue K-step t+2's loads, compute t.
#define ITER(t_, bc_, bs_)                                                  \
    {                                                                       \
        WAITBAR(6);                                                        \
        STAGE((t_) + 2, bs_);                                              \
        COMPUTE(bc_);                                                      \
    }

    // prologue: K-steps 0,1 into bufs 0,1 (12 loads in flight per thread)
    STAGE(0, 0);
    STAGE(1, 1);

#pragma unroll 1
    for (int t = 0; t < 15; t += 3) {
        ITER(t, 0, 2);
        ITER(t + 1, 1, 0);
        ITER(t + 2, 2, 1);
    }
    ITER(15, 0, 2);  // stages K-step 17 into buf 2
    // t = 16: outstanding = 16's 6 + 17's 6 -> drain 16's
    WAITBAR(6);
    COMPUTE(1);
    // t = 17: drain the rest
    WAITBAR(0);
    COMPUTE(2);

#undef STAGE
#undef COMPUTE
#undef WAITBAR
#undef ITER

    // epilogue: D row = quad*4+reg, col = lane&15 (verified)
#pragma unroll
    for (int i = 0; i < 4; ++i) {
#pragma unroll
        for (int rr = 0; rr < 4; ++rr) {
            const int mrow = mtile * 256 + wm + i * 16 + quad * 4 + rr;
            if (mrow < MTOT) {
                const int oh2 = mrow / OWD;
                const int ow2 = mrow - oh2 * OWD;
                float* op = Out + (((size_t)b * OWD + oh2) * OWD + ow2) * 128 + wn + l15;
#pragma unroll
                for (int j = 0; j < 4; ++j)
                    op[j * 16] = acc[i][j][rr];
            }
        }
    }
}

// ---------------------------------------------------------------------------
// Fallback (ws too small): fp32 X with in-kernel cvt (unchanged, verified).
// ---------------------------------------------------------------------------
__global__ __launch_bounds__(256) void conv_mfma(const float* __restrict__ X,
                                                 const uint16_t* __restrict__ Bt,
                                                 float* __restrict__ Out) {
    __shared__ __align__(16) uint16_t lA[128 * 64];
    __shared__ __align__(16) uint16_t lB[128 * 64];

    const int mtile = blockIdx.x;
    const int b     = blockIdx.y;
    const int tid   = threadIdx.x;
    const int lane  = tid & 63;
    const int wave  = tid >> 6;
    const int wm    = (wave & 1) << 6;
    const int wn    = (wave >> 1) << 6;
    const int l15   = lane & 15;
    const int quad  = lane >> 4;

    const int srow  = tid >> 1;
    const int shalf = tid & 1;

    int m = mtile * 128 + srow;
    if (m >= MTOT) m = MTOT - 1;
    const int oh = m / OWD;
    const int ow = m - oh * OWD;
    const float*    Xb = X + (((size_t)b * 128 + oh) * 128 + ow) * 128;
    const uint16_t* Bb = Bt + ((size_t)b * 128 + srow) * 1152 + shalf * 32;

    f32x4 acc[4][4];
#pragma unroll
    for (int i = 0; i < 4; ++i)
#pragma unroll
        for (int j = 0; j < 4; ++j)
            acc[i][j] = (f32x4){0.f, 0.f, 0.f, 0.f};

    for (int chunk = 0; chunk < 18; ++chunk) {
        const int rs = chunk >> 1;
        const int c0 = (chunk & 1) << 6;
        const int r  = rs / 3;
        const int s  = rs - r * 3;

        __syncthreads();
        {
            const float4* src = (const float4*)(Xb + (r * 128 + s) * 128 + c0 + shalf * 32);
            float4 v[8];
#pragma unroll
            for (int i = 0; i < 8; ++i) v[i] = src[i];
#pragma unroll
            for (int i = 0; i < 4; ++i) {
                uint4 p;
                p.x = pk2(v[2 * i].x, v[2 * i].y);
                p.y = pk2(v[2 * i].z, v[2 * i].w);
                p.z = pk2(v[2 * i + 1].x, v[2 * i + 1].y);
                p.w = pk2(v[2 * i + 1].z, v[2 * i + 1].w);
                const int ci = (shalf * 4 + i) ^ (srow & 7);
                *(uint4*)&lA[srow * 64 + ci * 8] = p;
            }
        }
        {
            const uint4* bsrc = (const uint4*)(Bb + rs * 128 + c0);
#pragma unroll
            for (int i = 0; i < 4; ++i) {
                const uint4 p = bsrc[i];
                const int ci = (shalf * 4 + i) ^ (srow & 7);
                *(uint4*)&lB[srow * 64 + ci * 8] = p;
            }
        }
        __syncthreads();

#pragma unroll
        for (int ksub = 0; ksub < 2; ++ksub) {
            bf16x8 af[4], bfr[4];
#pragma unroll
            for (int i = 0; i < 4; ++i) {
                const int row = wm + i * 16 + l15;
                const int ci  = (ksub * 4 + quad) ^ (row & 7);
                af[i] = *(const bf16x8*)&lA[row * 64 + ci * 8];
            }
#pragma unroll
            for (int j = 0; j < 4; ++j) {
                const int row = wn + j * 16 + l15;
                const int ci  = (ksub * 4 + quad) ^ (row & 7);
                bfr[j] = *(const bf16x8*)&lB[row * 64 + ci * 8];
            }
#pragma unroll
            for (int i = 0; i < 4; ++i)
#pragma unroll
                for (int j = 0; j < 4; ++j)
                    acc[i][j] = __builtin_amdgcn_mfma_f32_16x16x32_bf16(
                        af[i], bfr[j], acc[i][j], 0, 0, 0);
        }
    }

#pragma unroll
    for (int i = 0; i < 4; ++i) {
#pragma unroll
        for (int rr = 0; rr < 4; ++rr) {
            const int mrow = mtile * 128 + wm + i * 16 + quad * 4 + rr;
            if (mrow < MTOT) {
                const int oh2 = mrow / OWD;
                const int ow2 = mrow - oh2 * OWD;
                float* op = Out + (((size_t)b * OWD + oh2) * OWD + ow2) * 128 + wn + l15;
#pragma unroll
                for (int j = 0; j < 4; ++j)
                    op[j * 16] = acc[i][j][rr];
            }
        }
    }
}

extern "C" void kernel_launch(void* const* d_in, const int* in_sizes, int n_in,
                              void* d_out, int out_size, void* d_ws, size_t ws_size,
                              hipStream_t stream) {
    const float* X   = (const float*)d_in[0];   // [16,128,128,128]
    const float* Kin = (const float*)d_in[1];   // [16,3,3,128,128]
    float*       Out = (float*)d_out;           // [16,126,126,128]
    uint16_t*    Bt  = (uint16_t*)d_ws;         // bf16 [16][128][1152]
    uint16_t*    Xbf = Bt + BT_ELEMS;           // bf16 [16][128][128][128]

    kprep<<<dim3(9, 16), 256, 0, stream>>>(Kin, Bt);
    if (ws_size >= WS_NEEDED) {
        xprep<<<XBF_ELEMS / (256 * 8), 256, 0, stream>>>(X, Xbf);
        conv_mfma_e<<<dim3(63, 16), 512, 0, stream>>>(Xbf, Bt, Out);
    } else {
        conv_mfma<<<dim3(125, 16), 256, 0, stream>>>(X, Bt, Out);
    }
}

// Round 8
// 315.197 us; speedup vs baseline: 1.0508x; 1.0042x over previous
//
#include <hip/hip_runtime.h>
#include <cstdint>

#define OWD 126
#define MTOT 15876   // 126*126

typedef short bf16x8 __attribute__((ext_vector_type(8)));
typedef float f32x4  __attribute__((ext_vector_type(4)));

#define BT_ELEMS  (16u * 128u * 1152u)                 // 2,359,296 bf16
#define XBF_ELEMS (16u * 128u * 128u * 128u)           // 33,554,432 bf16
#define WS_NEEDED ((size_t)(BT_ELEMS + XBF_ELEMS) * 2) // ~71.8 MB

__device__ __forceinline__ uint16_t f2bf(float f) {
    union { float f; uint32_t u; } v;
    v.f = f;
    uint32_t u = v.u;
    return (uint16_t)((u + 0x7FFFu + ((u >> 16) & 1u)) >> 16);
}

__device__ __forceinline__ uint32_t pk2(float a, float b) {
    return (uint32_t)f2bf(a) | ((uint32_t)f2bf(b) << 16);
}

__device__ __forceinline__ void gl_lds16(const uint16_t* g, uint16_t* l) {
    __builtin_amdgcn_global_load_lds(
        (const __attribute__((address_space(1))) uint32_t*)g,
        (__attribute__((address_space(3))) uint32_t*)l, 16, 0, 0);
}

// ---------------------------------------------------------------------------
// Prep 1: kernel [16][9][128 c][128 n] fp32 -> Bt [16][128 n][1152 k] bf16
// ---------------------------------------------------------------------------
__global__ __launch_bounds__(256) void kprep(const float* __restrict__ Kin,
                                             uint16_t* __restrict__ Bt) {
    const int rs = blockIdx.x;   // 0..8
    const int b  = blockIdx.y;   // 0..15
    const int t  = threadIdx.x;
    const int n  = t & 127;
    const int og = t >> 7;

    const float* src = Kin + (((size_t)b * 9 + rs) << 14);
    uint16_t*    dst = Bt + ((size_t)b * 128 + n) * 1152 + rs * 128;

#pragma unroll
    for (int o = 0; o < 8; ++o) {
        const int oct = og * 8 + o;
        const float* s0 = src + (oct * 8) * 128 + n;
        uint4 p;
        p.x = pk2(s0[0 * 128], s0[1 * 128]);
        p.y = pk2(s0[2 * 128], s0[3 * 128]);
        p.z = pk2(s0[4 * 128], s0[5 * 128]);
        p.w = pk2(s0[6 * 128], s0[7 * 128]);
        *(uint4*)(dst + oct * 8) = p;
    }
}

// ---------------------------------------------------------------------------
// Prep 2: X fp32 NHWC -> bf16 NHWC (same layout), 8 elems/thread
// ---------------------------------------------------------------------------
__global__ __launch_bounds__(256) void xprep(const float* __restrict__ X,
                                             uint16_t* __restrict__ Xbf) {
    const size_t i = ((size_t)blockIdx.x * 256 + threadIdx.x) * 8;
    const float4 a = *(const float4*)(X + i);
    const float4 b = *(const float4*)(X + i + 4);
    uint4 p;
    p.x = pk2(a.x, a.y);
    p.y = pk2(a.z, a.w);
    p.z = pk2(b.x, b.y);
    p.w = pk2(b.z, b.w);
    *(uint4*)(Xbf + i) = p;
}

// ---------------------------------------------------------------------------
// Main (round 8): combine the two verified wins -- round 7's 8-wave block
// (256x128 tile, 2 waves/SIMD role diversity) and round 4's multi-block
// occupancy. BK=32 -> 36 K-chunks, 3 buffers x 24 KB = 72 KB LDS ->
// 2 blocks/CU (4 waves/SIMD): one block's barrier/drain bubbles are filled
// by the other block's compute (round 7 at 144 KB had 1 block/CU and ~35us
// of exposed latency over the pipe floors).
// Per buffer: A [256 rows][32 k] = 16 KB at [0,8192) elems, B [128][32] =
// 8 KB at [8192,12288). Staging: 3 gl_lds/thread/chunk (A passes p=0,1 ->
// rows p*128 + tid/4; B -> rows tid/4), pslot = tid&3, logical chunk
// kc = (tid&3) ^ ((tid>>3)&3)  [round-4-verified involution for BK=32].
// Reads: slot = quad ^ ((row>>1)&3) -- measured 0 bank conflicts (round 4).
// Counted sync: depth-2 prefetch, steady queue 6 loads/thread, per chunk
// { s_waitcnt vmcnt(3); s_barrier; sched_barrier } -- never drains to 0.
// Rotation/tail schedule byte-identical to round 4's proven pattern.
// ---------------------------------------------------------------------------
__global__ __launch_bounds__(512, 4) void conv_mfma_f(const uint16_t* __restrict__ Xbf,
                                                      const uint16_t* __restrict__ Bt,
                                                      float* __restrict__ Out) {
    __shared__ __align__(16) uint16_t lds[3][12288];  // 3 x 24 KB = 72 KB

    // XCD-aware bijective swizzle (nwg = 63*16 = 1008, 1008 % 8 == 0)
    const int id    = blockIdx.x + 63 * blockIdx.y;
    const int nid   = (id & 7) * 126 + (id >> 3);
    const int mtile = nid % 63;
    const int b     = nid / 63;

    const int tid  = threadIdx.x;
    const int lane = tid & 63;
    const int wave = tid >> 6;
    const int wm   = (wave & 3) << 6;   // 0/64/128/192
    const int wn   = (wave >> 2) << 6;  // 0/64
    const int l15  = lane & 15;
    const int quad = lane >> 4;

    // staging: thread t covers row t>>2 (within a 128-row pass), pslot t&3
    const int srow = tid >> 2;
    const int kc   = (tid & 3) ^ ((tid >> 3) & 3);
    const uint16_t* Asrc[2];
    const uint16_t* Bsrc1;
#pragma unroll
    for (int p = 0; p < 2; ++p) {
        const int row = p * 128 + srow;
        int m = mtile * 256 + row;
        if (m >= MTOT) m = MTOT - 1;
        const int oh = m / OWD, ow = m - oh * OWD;
        Asrc[p] = Xbf + (((size_t)b * 128 + oh) * 128 + ow) * 128 + kc * 8;
    }
    Bsrc1 = Bt + ((size_t)b * 128 + srow) * 1152 + kc * 8;
    const int dbase = tid * 8;  // elem offset within a pass (wave-uniform + lane*16B)

    f32x4 acc[4][4];
#pragma unroll
    for (int i = 0; i < 4; ++i)
#pragma unroll
        for (int j = 0; j < 4; ++j)
            acc[i][j] = (f32x4){0.f, 0.f, 0.f, 0.f};

    // chunk t (0..35): rs = t>>2, ch base c0 = (t&3)*32
#define STAGE(t_, bu_)                                                      \
    {                                                                       \
        const int rs_ = (t_) >> 2;                                         \
        const int c0_ = ((t_) & 3) << 5;                                   \
        const int r_  = (rs_ * 11) >> 5; /* rs/3 for rs<9 */               \
        const int s_  = rs_ - r_ * 3;                                      \
        const int ao_ = (r_ * 128 + s_) * 128 + c0_;                       \
        const int bo_ = rs_ * 128 + c0_;                                   \
        uint16_t* base_ = &lds[bu_][0];                                    \
        _Pragma("unroll")                                                  \
        for (int p_ = 0; p_ < 2; ++p_)                                     \
            gl_lds16(Asrc[p_] + ao_, base_ + p_ * 4096 + dbase);           \
        gl_lds16(Bsrc1 + bo_, base_ + 8192 + dbase);                       \
    }

#define COMPUTE(bu_)                                                        \
    {                                                                       \
        bf16x8 af[4], bfr[4];                                              \
        _Pragma("unroll")                                                  \
        for (int i_ = 0; i_ < 4; ++i_) {                                   \
            const int row_ = wm + i_ * 16 + l15;                           \
            const int sl_  = quad ^ ((row_ >> 1) & 3);                     \
            af[i_] = *(const bf16x8*)&lds[bu_][row_ * 32 + sl_ * 8];       \
        }                                                                  \
        _Pragma("unroll")                                                  \
        for (int j_ = 0; j_ < 4; ++j_) {                                   \
            const int row_ = wn + j_ * 16 + l15;                           \
            const int sl_  = quad ^ ((row_ >> 1) & 3);                     \
            bfr[j_] = *(const bf16x8*)&lds[bu_][8192 + row_ * 32 + sl_ * 8];\
        }                                                                  \
        __builtin_amdgcn_s_setprio(1);                                     \
        _Pragma("unroll")                                                  \
        for (int i_ = 0; i_ < 4; ++i_)                                     \
            _Pragma("unroll")                                              \
            for (int j_ = 0; j_ < 4; ++j_)                                 \
                acc[i_][j_] = __builtin_amdgcn_mfma_f32_16x16x32_bf16(     \
                    af[i_], bfr[j_], acc[i_][j_], 0, 0, 0);                \
        __builtin_amdgcn_s_setprio(0);                                     \
    }

#define WAITBAR(n_)                                                         \
    asm volatile("s_waitcnt vmcnt(" #n_ ")" ::: "memory");                 \
    __builtin_amdgcn_s_barrier();                                          \
    __builtin_amdgcn_sched_barrier(0);

    // ITER(t): drain chunk t's 3 loads (leaves t+1's 3 in flight across the
    // barrier), issue chunk t+2's loads, compute t.
#define ITER(t_, bc_, bs_)                                                  \
    {                                                                       \
        WAITBAR(3);                                                        \
        STAGE((t_) + 2, bs_);                                              \
        COMPUTE(bc_);                                                      \
    }

    // prologue: chunks 0,1 into bufs 0,1 (6 loads in flight per thread)
    STAGE(0, 0);
    STAGE(1, 1);

    // steady state: compute t from buf t%3, stage t+2 into (t+2)%3.
#pragma unroll 1
    for (int t = 0; t < 33; t += 3) {
        ITER(t, 0, 2);
        ITER(t + 1, 1, 0);
        ITER(t + 2, 2, 1);
    }
    ITER(33, 0, 2);  // stages chunk 35 into buf 2
    // t = 34: outstanding = 34's 3 + 35's 3 -> drain 34's
    WAITBAR(3);
    COMPUTE(1);
    // t = 35: drain the rest
    WAITBAR(0);
    COMPUTE(2);

#undef STAGE
#undef COMPUTE
#undef WAITBAR
#undef ITER

    // epilogue: D row = quad*4+reg, col = lane&15 (verified)
#pragma unroll
    for (int i = 0; i < 4; ++i) {
#pragma unroll
        for (int rr = 0; rr < 4; ++rr) {
            const int mrow = mtile * 256 + wm + i * 16 + quad * 4 + rr;
            if (mrow < MTOT) {
                const int oh2 = mrow / OWD;
                const int ow2 = mrow - oh2 * OWD;
                float* op = Out + (((size_t)b * OWD + oh2) * OWD + ow2) * 128 + wn + l15;
#pragma unroll
                for (int j = 0; j < 4; ++j)
                    op[j * 16] = acc[i][j][rr];
            }
        }
    }
}

// ---------------------------------------------------------------------------
// Fallback (ws too small): fp32 X with in-kernel cvt (unchanged, verified).
// ---------------------------------------------------------------------------
__global__ __launch_bounds__(256) void conv_mfma(const float* __restrict__ X,
                                                 const uint16_t* __restrict__ Bt,
                                                 float* __restrict__ Out) {
    __shared__ __align__(16) uint16_t lA[128 * 64];
    __shared__ __align__(16) uint16_t lB[128 * 64];

    const int mtile = blockIdx.x;
    const int b     = blockIdx.y;
    const int tid   = threadIdx.x;
    const int lane  = tid & 63;
    const int wave  = tid >> 6;
    const int wm    = (wave & 1) << 6;
    const int wn    = (wave >> 1) << 6;
    const int l15   = lane & 15;
    const int quad  = lane >> 4;

    const int srow  = tid >> 1;
    const int shalf = tid & 1;

    int m = mtile * 128 + srow;
    if (m >= MTOT) m = MTOT - 1;
    const int oh = m / OWD;
    const int ow = m - oh * OWD;
    const float*    Xb = X + (((size_t)b * 128 + oh) * 128 + ow) * 128;
    const uint16_t* Bb = Bt + ((size_t)b * 128 + srow) * 1152 + shalf * 32;

    f32x4 acc[4][4];
#pragma unroll
    for (int i = 0; i < 4; ++i)
#pragma unroll
        for (int j = 0; j < 4; ++j)
            acc[i][j] = (f32x4){0.f, 0.f, 0.f, 0.f};

    for (int chunk = 0; chunk < 18; ++chunk) {
        const int rs = chunk >> 1;
        const int c0 = (chunk & 1) << 6;
        const int r  = rs / 3;
        const int s  = rs - r * 3;

        __syncthreads();
        {
            const float4* src = (const float4*)(Xb + (r * 128 + s) * 128 + c0 + shalf * 32);
            float4 v[8];
#pragma unroll
            for (int i = 0; i < 8; ++i) v[i] = src[i];
#pragma unroll
            for (int i = 0; i < 4; ++i) {
                uint4 p;
                p.x = pk2(v[2 * i].x, v[2 * i].y);
                p.y = pk2(v[2 * i].z, v[2 * i].w);
                p.z = pk2(v[2 * i + 1].x, v[2 * i + 1].y);
                p.w = pk2(v[2 * i + 1].z, v[2 * i + 1].w);
                const int ci = (shalf * 4 + i) ^ (srow & 7);
                *(uint4*)&lA[srow * 64 + ci * 8] = p;
            }
        }
        {
            const uint4* bsrc = (const uint4*)(Bb + rs * 128 + c0);
#pragma unroll
            for (int i = 0; i < 4; ++i) {
                const uint4 p = bsrc[i];
                const int ci = (shalf * 4 + i) ^ (srow & 7);
                *(uint4*)&lB[srow * 64 + ci * 8] = p;
            }
        }
        __syncthreads();

#pragma unroll
        for (int ksub = 0; ksub < 2; ++ksub) {
            bf16x8 af[4], bfr[4];
#pragma unroll
            for (int i = 0; i < 4; ++i) {
                const int row = wm + i * 16 + l15;
                const int ci  = (ksub * 4 + quad) ^ (row & 7);
                af[i] = *(const bf16x8*)&lA[row * 64 + ci * 8];
            }
#pragma unroll
            for (int j = 0; j < 4; ++j) {
                const int row = wn + j * 16 + l15;
                const int ci  = (ksub * 4 + quad) ^ (row & 7);
                bfr[j] = *(const bf16x8*)&lB[row * 64 + ci * 8];
            }
#pragma unroll
            for (int i = 0; i < 4; ++i)
#pragma unroll
                for (int j = 0; j < 4; ++j)
                    acc[i][j] = __builtin_amdgcn_mfma_f32_16x16x32_bf16(
                        af[i], bfr[j], acc[i][j], 0, 0, 0);
        }
    }

#pragma unroll
    for (int i = 0; i < 4; ++i) {
#pragma unroll
        for (int rr = 0; rr < 4; ++rr) {
            const int mrow = mtile * 128 + wm + i * 16 + quad * 4 + rr;
            if (mrow < MTOT) {
                const int oh2 = mrow / OWD;
                const int ow2 = mrow - oh2 * OWD;
                float* op = Out + (((size_t)b * OWD + oh2) * OWD + ow2) * 128 + wn + l15;
#pragma unroll
                for (int j = 0; j < 4; ++j)
                    op[j * 16] = acc[i][j][rr];
            }
        }
    }
}

extern "C" void kernel_launch(void* const* d_in, const int* in_sizes, int n_in,
                              void* d_out, int out_size, void* d_ws, size_t ws_size,
                              hipStream_t stream) {
    const float* X   = (const float*)d_in[0];   // [16,128,128,128]
    const float* Kin = (const float*)d_in[1];   // [16,3,3,128,128]
    float*       Out = (float*)d_out;           // [16,126,126,128]
    uint16_t*    Bt  = (uint16_t*)d_ws;         // bf16 [16][128][1152]
    uint16_t*    Xbf = Bt + BT_ELEMS;           // bf16 [16][128][128][128]

    kprep<<<dim3(9, 16), 256, 0, stream>>>(Kin, Bt);
    if (ws_size >= WS_NEEDED) {
        xprep<<<XBF_ELEMS / (256 * 8), 256, 0, stream>>>(X, Xbf);
        conv_mfma_f<<<dim3(63, 16), 512, 0, stream>>>(Xbf, Bt, Out);
    } else {
        conv_mfma<<<dim3(125, 16), 256, 0, stream>>>(X, Bt, Out);
    }
}